// Round 12
// baseline (784.371 us; speedup 1.0000x reference)
//
#include <hip/hip_runtime.h>
#include <hip/hip_bf16.h>
#include <math.h>

#define B_   2
#define S_   2048
#define H_   2048
#define NH   16
#define HD   128
#define ROWS (B_ * S_)   // 4096
#define F3   (3 * H_)    // 6144
#define KS   2048        // inner dim of both projection GEMMs (per split term)

typedef _Float16 f16x8 __attribute__((ext_vector_type(8)));
typedef float    f32x4  __attribute__((ext_vector_type(4)));
typedef float    f32x16 __attribute__((ext_vector_type(16)));

union H2 { unsigned u; _Float16 h[2]; };
union H4 { ushort4 s4; _Float16 h[4]; };
union H4b { uint2 u2; _Float16 h[4]; };
union PU { unsigned u[4]; f16x8 v8; };

__device__ __forceinline__ void gl_lds16(const void* g, void* l) {
  __builtin_amdgcn_global_load_lds(
      (const __attribute__((address_space(1))) void*)g,
      (__attribute__((address_space(3))) void*)l, 16, 0, 0);
}

// ---------------------------------------------------------------------------
// fp8 e4m3fn RNE quantization -> representable value (exact in fp16)
// ---------------------------------------------------------------------------
__device__ __forceinline__ float quant_e4m3(float x) {
  float ax = fabsf(x);
  float q;
  if (ax < 0.015625f) {
    q = rintf(ax * 512.0f) * (1.0f / 512.0f);
  } else {
    unsigned eb = __float_as_uint(ax) & 0x7f800000u;
    float quantum = __uint_as_float(eb - (3u << 23));      // 2^(e-3)
    q = rintf(ax / quantum) * quantum;
    if (q > 448.0f) q = 448.0f;
  }
  return copysignf(q, x);
}

// ---------------------------------------------------------------------------
// Fused prep: blocks [0,8192) = x -> A1 hi/lo split (elementwise);
// blocks [8192,11264) = W_qkv -> B1t hi/lo split TRANSPOSED (n-tile,k-tile).
// (W_out's split cannot join: its destination aliases qkv's region.)
// ---------------------------------------------------------------------------
__global__ __launch_bounds__(256) void prep_split(
    const float* __restrict__ x, const float* __restrict__ Wqkv,
    _Float16* __restrict__ A1hi, _Float16* __restrict__ A1lo,
    _Float16* __restrict__ B1thi, _Float16* __restrict__ B1tlo) {
  __shared__ _Float16 ht[64][72];
  __shared__ _Float16 lt[64][72];
  const int t = threadIdx.x;
  const int bid = blockIdx.x;
  if (bid < 8192) {
    const size_t i = (size_t)bid * 256 + t;
    float4 v = ((const float4*)x)[i];
    H4 h, l;
    h.h[0] = (_Float16)v.x; l.h[0] = (_Float16)(v.x - (float)h.h[0]);
    h.h[1] = (_Float16)v.y; l.h[1] = (_Float16)(v.y - (float)h.h[1]);
    h.h[2] = (_Float16)v.z; l.h[2] = (_Float16)(v.z - (float)h.h[2]);
    h.h[3] = (_Float16)v.w; l.h[3] = (_Float16)(v.w - (float)h.h[3]);
    ((ushort4*)A1hi)[i] = h.s4;
    ((ushort4*)A1lo)[i] = l.s4;
  } else {
    const int idx = bid - 8192;            // 0..3071
    const int n0 = (idx % 96) * 64, k0 = (idx / 96) * 64;
    const int K = H_, N = F3;
#pragma unroll
    for (int p = 0; p < 4; p++) {
      const int k = p * 16 + (t >> 4);
      const int n = (t & 15) * 4;
      float4 v = *(const float4*)(Wqkv + (size_t)(k0 + k) * N + n0 + n);
      _Float16 h0 = (_Float16)v.x, h1 = (_Float16)v.y,
               h2 = (_Float16)v.z, h3 = (_Float16)v.w;
      ht[n + 0][k] = h0; lt[n + 0][k] = (_Float16)(v.x - (float)h0);
      ht[n + 1][k] = h1; lt[n + 1][k] = (_Float16)(v.y - (float)h1);
      ht[n + 2][k] = h2; lt[n + 2][k] = (_Float16)(v.z - (float)h2);
      ht[n + 3][k] = h3; lt[n + 3][k] = (_Float16)(v.w - (float)h3);
    }
    __syncthreads();
#pragma unroll
    for (int it = 0; it < 2; it++) {
      const int idx2 = it * 256 + t;
      const int r = idx2 >> 3, c = (idx2 & 7) * 8;
      *(uint4*)(B1thi + (size_t)(n0 + r) * K + k0 + c) = *(const uint4*)&ht[r][c];
      *(uint4*)(B1tlo + (size_t)(n0 + r) * K + k0 + c) = *(const uint4*)&lt[r][c];
    }
  }
}

// ---------------------------------------------------------------------------
// fp32 K x N -> fp16 hi/lo, TRANSPOSED to N x K (kept for W_out: its dest
// aliases qkv's region, so it must run after quant_qkv)
// ---------------------------------------------------------------------------
__global__ __launch_bounds__(256) void split_tr(
    const float* __restrict__ in, _Float16* __restrict__ hi,
    _Float16* __restrict__ lo, int K, int N) {
  __shared__ _Float16 ht[64][72];
  __shared__ _Float16 lt[64][72];
  const int t = threadIdx.x;
  const int n0 = blockIdx.x * 64, k0 = blockIdx.y * 64;
#pragma unroll
  for (int p = 0; p < 4; p++) {
    const int k = p * 16 + (t >> 4);
    const int n = (t & 15) * 4;
    float4 v = *(const float4*)(in + (size_t)(k0 + k) * N + n0 + n);
    _Float16 h0 = (_Float16)v.x, h1 = (_Float16)v.y,
             h2 = (_Float16)v.z, h3 = (_Float16)v.w;
    ht[n + 0][k] = h0; lt[n + 0][k] = (_Float16)(v.x - (float)h0);
    ht[n + 1][k] = h1; lt[n + 1][k] = (_Float16)(v.y - (float)h1);
    ht[n + 2][k] = h2; lt[n + 2][k] = (_Float16)(v.z - (float)h2);
    ht[n + 3][k] = h3; lt[n + 3][k] = (_Float16)(v.w - (float)h3);
  }
  __syncthreads();
#pragma unroll
  for (int it = 0; it < 2; it++) {
    const int idx = it * 256 + t;
    const int r = idx >> 3, c = (idx & 7) * 8;
    *(uint4*)(hi + (size_t)(n0 + r) * K + k0 + c) = *(const uint4*)&ht[r][c];
    *(uint4*)(lo + (size_t)(n0 + r) * K + k0 + c) = *(const uint4*)&lt[r][c];
  }
}

// ---------------------------------------------------------------------------
// MFMA split-fp16 GEMM, round-16: round-7 triple-buffer geometry (conflict-
// free, counted vmcnt(6), bit-identical accumulation order) + the m201-style
// PHASE-SPLIT body: per kc, TWO phases each {8 ds_read frags || stage-half ->
// s_barrier -> lgkmcnt(0)+sched_barrier(0) -> setprio(1) 16 MFMA setprio(0)
// -> s_barrier}. Barriers act as compiler fences (the r10 graft failed
// because the compiler re-sank unfenced prefetch reads). Waves anti-phase:
// one wave's ds_reads overlap the sibling wave's MFMA cluster (m196 lever).
// Fused per-segment max|C| epilogue kept (mx != nullptr).
// ---------------------------------------------------------------------------
#define STAGE_A(tt, dst) do {                                                  \
    const _Float16* As_ = ((tt) < 64) ? Ahi : Alo;                             \
    const size_t so_ = (size_t)(row0 + wave * 8 + srow) * KS +                 \
                       (((tt) & 31) << 6) + schunk;                            \
    _Float16* db_ = (dst) + wave * 512;                                        \
    gl_lds16(As_ + so_,                    db_);                               \
    gl_lds16(As_ + so_ + (size_t)64 * KS,  db_ + 4096);                        \
    gl_lds16(As_ + so_ + (size_t)128 * KS, db_ + 8192);                       \
    gl_lds16(As_ + so_ + (size_t)192 * KS, db_ + 12288);                       \
  } while (0)

#define STAGE_B(tt, dst) do {                                                  \
    const _Float16* Bs_ = ((((tt) >> 5)) == 1) ? Btlo : Bthi;                  \
    const size_t so_ = (size_t)(col0 + wave * 8 + srow) * KS +                 \
                       (((tt) & 31) << 6) + schunk;                            \
    _Float16* db_ = (dst) + 16384 + wave * 512;                                \
    gl_lds16(Bs_ + so_,                    db_);                               \
    gl_lds16(Bs_ + so_ + (size_t)64 * KS,  db_ + 4096);                        \
  } while (0)

__global__ __launch_bounds__(512, 2) void gemm_split256(
    const _Float16* __restrict__ Ahi, const _Float16* __restrict__ Alo,
    const _Float16* __restrict__ Bthi, const _Float16* __restrict__ Btlo,
    float* __restrict__ C, const float* __restrict__ bias,
    unsigned* mx, int N, int has_bias) {
  __shared__ __align__(16) _Float16 lds[73728];   // 3 x 48 KiB = 144 KiB
  const int t = threadIdx.x;
  const int wave = t >> 6, lane = t & 63;
  const int l15 = lane & 15, g = lane >> 4;
  const int wm = wave >> 1, wn = wave & 1;    // 4M x 2N wave grid

  // XCD-aware bijective tile swizzle (both grids are multiples of 8)
  const int gx = gridDim.x;
  const int nwg = gx * gridDim.y;
  const int bid = blockIdx.y * gx + blockIdx.x;
  const int tile = (bid & 7) * (nwg >> 3) + (bid >> 3);
  const int row0 = (tile / gx) * 256, col0 = (tile % gx) * 128;

  // staging coords: 8 rows x 128B per wave per load; source chunk XOR-swizzled
  const int srow = lane >> 3;                    // row&7 of staged row
  const int schunk = ((lane & 7) ^ srow) << 3;   // halves

  f32x4 acc[4][4] = {};

  _Float16* bufA = lds;                 // tile kc   (compute)
  _Float16* bufB = lds + 24576;         // tile kc+1 (in flight / landed)
  _Float16* bufC = lds + 49152;         // tile kc+2 (stage target)

  // prologue: tile0 -> bufA, tile1 -> bufB; retire tile0 (6), keep tile1 flying
  STAGE_A(0, bufA);
  STAGE_B(0, bufA);
  STAGE_A(1, bufB);
  STAGE_B(1, bufB);
  asm volatile("s_waitcnt vmcnt(6)" ::: "memory");
  __builtin_amdgcn_s_barrier();

  for (int kc = 0; kc < 96; kc++) {
    const _Float16* Ab = bufA;
    const _Float16* Bb = bufA + 16384;
    // ---------------- phase 0 : k-half 0 ----------------
    f16x8 af0[4], bf0[4];
#pragma unroll
    for (int i = 0; i < 4; i++) {
      const int r_ = wm * 64 + i * 16 + l15;
      af0[i] = *(const f16x8*)(Ab + r_ * 64 + ((g ^ (r_ & 7)) << 3));
    }
#pragma unroll
    for (int j = 0; j < 4; j++) {
      const int r_ = wn * 64 + j * 16 + l15;
      bf0[j] = *(const f16x8*)(Bb + r_ * 64 + ((g ^ (r_ & 7)) << 3));
    }
    if (kc + 2 < 96) STAGE_A(kc + 2, bufC);
    __builtin_amdgcn_s_barrier();
    asm volatile("s_waitcnt lgkmcnt(0)" ::: "memory");
    __builtin_amdgcn_sched_barrier(0);
    __builtin_amdgcn_s_setprio(1);
#pragma unroll
    for (int i = 0; i < 4; i++)
#pragma unroll
      for (int j = 0; j < 4; j++)
        acc[i][j] = __builtin_amdgcn_mfma_f32_16x16x32_f16(af0[i], bf0[j], acc[i][j], 0, 0, 0);
    __builtin_amdgcn_s_setprio(0);
    __builtin_amdgcn_s_barrier();
    // ---------------- phase 1 : k-half 1 ----------------
    f16x8 af1[4], bf1[4];
#pragma unroll
    for (int i = 0; i < 4; i++) {
      const int r_ = wm * 64 + i * 16 + l15;
      af1[i] = *(const f16x8*)(Ab + r_ * 64 + (((4 ^ g) ^ (r_ & 7)) << 3));
    }
#pragma unroll
    for (int j = 0; j < 4; j++) {
      const int r_ = wn * 64 + j * 16 + l15;
      bf1[j] = *(const f16x8*)(Bb + r_ * 64 + (((4 ^ g) ^ (r_ & 7)) << 3));
    }
    if (kc + 2 < 96) STAGE_B(kc + 2, bufC);
    __builtin_amdgcn_s_barrier();
    asm volatile("s_waitcnt lgkmcnt(0)" ::: "memory");
    __builtin_amdgcn_sched_barrier(0);
    __builtin_amdgcn_s_setprio(1);
#pragma unroll
    for (int i = 0; i < 4; i++)
#pragma unroll
      for (int j = 0; j < 4; j++)
        acc[i][j] = __builtin_amdgcn_mfma_f32_16x16x32_f16(af1[i], bf1[j], acc[i][j], 0, 0, 0);
    __builtin_amdgcn_s_setprio(0);
    // retire tile kc+1's 6 loads; keep tile kc+2's 6 in flight
    if (kc < 94) { asm volatile("s_waitcnt vmcnt(6)" ::: "memory"); }
    else         { asm volatile("s_waitcnt vmcnt(0)" ::: "memory"); }
    __builtin_amdgcn_s_barrier();
    _Float16* tmp = bufA; bufA = bufB; bufB = bufC; bufC = tmp;
  }

  float bmax = 0.0f;
#pragma unroll
  for (int j = 0; j < 4; j++) {
    const int col = col0 + wn * 64 + j * 16 + l15;
    const float bv = has_bias ? bias[col] : 0.0f;
#pragma unroll
    for (int i = 0; i < 4; i++) {
      const int rbase = row0 + wm * 64 + i * 16 + g * 4;
#pragma unroll
      for (int r = 0; r < 4; r++) {
        const float v = acc[i][j][r] + bv;
        C[(size_t)(rbase + r) * N + col] = v;
        bmax = fmaxf(bmax, fabsf(v));
      }
    }
  }

  // fused per-segment max|.| (gemm1 only): block lies wholly in segment col0>>11
  if (mx) {
    __syncthreads();                 // K-loop done; LDS free for reduction
    float* red = (float*)lds;
    red[t] = bmax;
    __syncthreads();
    for (int s2 = 256; s2 > 0; s2 >>= 1) {
      if (t < s2) red[t] = fmaxf(red[t], red[t + s2]);
      __syncthreads();
    }
    if (t == 0) atomicMax(mx + (col0 >> 11), __float_as_uint(red[0]));
  }
}

// ---------------------------------------------------------------------------
// Fused quantization: Q,K segments -> q8/k8 [bh][s][d]; V -> v8t[bh][d][s]
// ---------------------------------------------------------------------------
__global__ __launch_bounds__(256) void quant_qkv(
    const float* __restrict__ qkv, const unsigned* __restrict__ mx,
    _Float16* __restrict__ q8, _Float16* __restrict__ k8,
    _Float16* __restrict__ v8t) {
  __shared__ _Float16 tile[64 * 72];
  const int t = threadIdx.x;
  const int bid = blockIdx.x;

  if (bid < 16384) {
    // ---- Q/K path ----
    const size_t base = ((size_t)bid * 256 + t) * 4;
    const int row = (int)(base >> 12);
    const int col = (int)(base & 4095);
    const int seg = col >> 11;
    const int c2 = col & 2047;
    const int h = c2 >> 7, d = c2 & 127;
    const int b = row >> 11, s = row & 2047;
    const float scale = __uint_as_float(mx[seg]) / 448.0f;
    float4 v = *(const float4*)(qkv + (size_t)row * F3 + col);
    H4 r;
    r.h[0] = (_Float16)quant_e4m3(v.x / scale);
    r.h[1] = (_Float16)quant_e4m3(v.y / scale);
    r.h[2] = (_Float16)quant_e4m3(v.z / scale);
    r.h[3] = (_Float16)quant_e4m3(v.w / scale);
    _Float16* dst = seg ? k8 : q8;
    const size_t di = ((size_t)((b * NH + h) * S_) + s) * HD + d;
    *(ushort4*)(dst + di) = r.s4;
  } else {
    // ---- V path (transposed store) ----
    const int bt = bid - 16384;
    const int dtile = bt & 1;
    const int stile = (bt >> 1) & 31;
    const int bh = bt >> 6;
    const int b = bh >> 4, h = bh & 15;
    const int s0 = stile * 64, d0 = dtile * 64;
    const float scale = __uint_as_float(mx[2]) / 448.0f;

#pragma unroll
    for (int r = 0; r < 4; r++) {
      const int s = s0 + r * 16 + (t >> 4);
      const int dl = (t & 15) * 4;
      float4 v = *(const float4*)(qkv + (size_t)(b * S_ + s) * F3 + 4096 + h * HD + d0 + dl);
      tile[(dl + 0) * 72 + r * 16 + (t >> 4)] = (_Float16)quant_e4m3(v.x / scale);
      tile[(dl + 1) * 72 + r * 16 + (t >> 4)] = (_Float16)quant_e4m3(v.y / scale);
      tile[(dl + 2) * 72 + r * 16 + (t >> 4)] = (_Float16)quant_e4m3(v.z / scale);
      tile[(dl + 3) * 72 + r * 16 + (t >> 4)] = (_Float16)quant_e4m3(v.w / scale);
    }
    __syncthreads();
#pragma unroll
    for (int j = 0; j < 2; j++) {
      const int wi = j * 256 + t;
      const int dl = wi >> 3;
      const int sch = (wi & 7) * 8;
      uint4 val = *(const uint4*)(tile + dl * 72 + sch);
      *(uint4*)(v8t + (size_t)bh * (HD * S_) + (size_t)(d0 + dl) * S_ + s0 + sch) = val;
    }
  }
}

// ---------------------------------------------------------------------------
// MFMA flash attention (round-15 version, unchanged this round)
// ---------------------------------------------------------------------------
__global__ __launch_bounds__(256, 2) void attn_kernel(
    const _Float16* __restrict__ q8, const _Float16* __restrict__ k8,
    const _Float16* __restrict__ v8t, const unsigned* __restrict__ mx,
    _Float16* __restrict__ oHi, _Float16* __restrict__ oLo) {
  __shared__ __align__(16) char ldsb[65536];
  // K buffers: ldsb + {0, 16384}   : [64 keys][128 halves], chunk^=(row&7)
  // V buffers: ldsb + {32768, 49152}: [128 d][64 halves],   chunk^=(row&7)

  const int t = threadIdx.x;        // 0..255
  const int wave = t >> 6;          // 0..3
  const int lane = t & 63;
  const int l31 = lane & 31;
  const int hf = lane >> 5;

  const int qt = blockIdx.x & 15;
  const int bh = blockIdx.x >> 4;
  const int b = bh >> 4, h = bh & 15;
  const int q0 = qt * 128 + wave * 32;   // this wave's 32 queries

  const float qs = __uint_as_float(mx[0]) * (1.0f / 448.0f);
  const float ks = __uint_as_float(mx[1]) * (1.0f / 448.0f);
  const float vs = __uint_as_float(mx[2]) * (1.0f / 448.0f);
  const float sfac = qs * ks * 0.08838834764831843f;   // 1/sqrt(128)

  // Q fragments (B-layout): Q[q=l31][d = st*16 + hf*8 + j]
  f16x8 qf[8];
  {
    const _Float16* qp = q8 + ((size_t)(bh * S_) + q0 + l31) * HD + hf * 8;
#pragma unroll
    for (int st = 0; st < 8; st++)
      qf[st] = *(const f16x8*)(qp + st * 16);
  }

  f32x16 acc[4] = {};
  float m_base = 0.0f;
  float l_run = 0.0f;

  const size_t kB_ = (size_t)(bh * S_) * HD;
  const size_t vB_ = (size_t)bh * (HD * S_);
  // per-thread staging coordinates
  const int k_key = t >> 4;            // + r*16 ; row&7 = k_key&7
  const int k_dch = (t & 15) * 8;      // global chunk offset (halves)
  const int k_wch = (((t & 15) ^ (k_key & 7)) << 3);   // swizzled LDS chunk
  const int v_d   = t >> 3;            // + r*32 ; row&7 = v_d&7
  const int v_sch = (t & 7) * 8;       // global chunk offset (halves)
  const int v_wch = (((t & 7) ^ (v_d & 7)) << 3);      // swizzled LDS chunk

  const int NT = S_ / 64;              // 32
  uint4 kp[4], vp[4];

  // prologue: load tile 0, write -> buffers[0], issue tile 1 loads, barrier
#pragma unroll
  for (int r = 0; r < 4; r++)
    kp[r] = *(const uint4*)(k8 + kB_ + (size_t)(r * 16 + k_key) * HD + k_dch);
#pragma unroll
  for (int r = 0; r < 4; r++)
    vp[r] = *(const uint4*)(v8t + vB_ + (size_t)(r * 32 + v_d) * S_ + v_sch);
  {
    _Float16* K0 = (_Float16*)ldsb;
    _Float16* V0 = (_Float16*)(ldsb + 32768);
#pragma unroll
    for (int r = 0; r < 4; r++)
      *(uint4*)(K0 + (r * 16 + k_key) * 128 + k_wch) = kp[r];
#pragma unroll
    for (int r = 0; r < 4; r++)
      *(uint4*)(V0 + (r * 32 + v_d) * 64 + v_wch) = vp[r];
  }
#pragma unroll
  for (int r = 0; r < 4; r++)
    kp[r] = *(const uint4*)(k8 + kB_ + (size_t)(64 + r * 16 + k_key) * HD + k_dch);
#pragma unroll
  for (int r = 0; r < 4; r++)
    vp[r] = *(const uint4*)(v8t + vB_ + (size_t)(r * 32 + v_d) * S_ + 64 + v_sch);
  __syncthreads();

  for (int kt = 0; kt < NT; kt++) {
    const _Float16* Klds  = (const _Float16*)(ldsb + (kt & 1) * 16384);
    const _Float16* VTlds = (const _Float16*)(ldsb + 32768 + (kt & 1) * 16384);
    // write tile kt+1 (in kp/vp) into the other buffer; overlaps compute
    if (kt + 1 < NT) {
      _Float16* Kn = (_Float16*)(ldsb + ((kt + 1) & 1) * 16384);
      _Float16* Vn = (_Float16*)(ldsb + 32768 + ((kt + 1) & 1) * 16384);
#pragma unroll
      for (int r = 0; r < 4; r++)
        *(uint4*)(Kn + (r * 16 + k_key) * 128 + k_wch) = kp[r];
#pragma unroll
      for (int r = 0; r < 4; r++)
        *(uint4*)(Vn + (r * 32 + v_d) * 64 + v_wch) = vp[r];
    }
    // issue tile kt+2's global loads (consumed next iteration)
    if (kt + 2 < NT) {
      const int nk = (kt + 2) * 64;
#pragma unroll
      for (int r = 0; r < 4; r++)
        kp[r] = *(const uint4*)(k8 + kB_ + (size_t)(nk + r * 16 + k_key) * HD + k_dch);
#pragma unroll
      for (int r = 0; r < 4; r++)
        vp[r] = *(const uint4*)(v8t + vB_ + (size_t)(r * 32 + v_d) * S_ + nk + v_sch);
    }

#pragma unroll
    for (int sub = 0; sub < 2; sub++) {
      const int ksub = sub * 32;
      // ---- S^T = K . Q^T ----  (K row = ksub+l31, chunk = st*2+hf)
      f32x16 s = {};
      __builtin_amdgcn_s_setprio(1);
#pragma unroll
      for (int st = 0; st < 8; st++) {
        const int krow = ksub + l31;
        f16x8 af = *(const f16x8*)(Klds + krow * 128 +
                                   (((st * 2 + hf) ^ (krow & 7)) << 3));
        s = __builtin_amdgcn_mfma_f32_32x32x16_f16(af, qf[st], s, 0, 0, 0);
      }
      __builtin_amdgcn_s_setprio(0);
      // prefetch first V fragments (dt=0): row = l31, chunk = sub*4 + c*2 + hf
      f16x8 vf0 = *(const f16x8*)(VTlds + l31 * 64 +
                                  (((sub * 4 + 0 * 2 + hf) ^ (l31 & 7)) << 3));
      f16x8 vf1 = *(const f16x8*)(VTlds + l31 * 64 +
                                  (((sub * 4 + 1 * 2 + hf) ^ (l31 & 7)) << 3));
      // ---- fixed-base softmax weights ----
      float p[16];
      if (kt == 0 && sub == 0) {
        float tmax = -3.0e38f;
#pragma unroll
        for (int i = 0; i < 16; i++) {
          p[i] = s[i] * sfac;
          tmax = fmaxf(tmax, p[i]);
        }
        tmax = fmaxf(tmax, __shfl_xor(tmax, 32));
        m_base = tmax;
        float rs = 0.0f;
#pragma unroll
        for (int i = 0; i < 16; i++) {
          p[i] = __expf(p[i] - tmax);
          rs += p[i];
        }
        l_run += rs;
      } else {
        const float mb = m_base;
        float rs = 0.0f;
#pragma unroll
        for (int i = 0; i < 16; i++) {
          p[i] = fminf(__expf(fmaf(s[i], sfac, -mb)), 60000.0f);
          rs += p[i];
        }
        l_run += rs;
      }
      // ---- pack + cross-half exchange -> P^T B-frags (keys ascending) ----
      f16x8 pf[2];
#pragma unroll
      for (int c = 0; c < 2; c++) {
        const int c8 = c * 8;
        const int sidx = hf ? 0 : 4;
        const int oidx = hf ? 4 : 0;
        H2 s0h, s1h, o0h, o1h;
        s0h.h[0] = (_Float16)p[c8 + sidx];     s0h.h[1] = (_Float16)p[c8 + sidx + 1];
        s1h.h[0] = (_Float16)p[c8 + sidx + 2]; s1h.h[1] = (_Float16)p[c8 + sidx + 3];
        o0h.h[0] = (_Float16)p[c8 + oidx];     o0h.h[1] = (_Float16)p[c8 + oidx + 1];
        o1h.h[0] = (_Float16)p[c8 + oidx + 2]; o1h.h[1] = (_Float16)p[c8 + oidx + 3];
        unsigned r0 = (unsigned)__shfl_xor((int)s0h.u, 32);
        unsigned r1 = (unsigned)__shfl_xor((int)s1h.u, 32);
        PU pu;
        if (hf == 0) { pu.u[0] = o0h.u; pu.u[1] = o1h.u; pu.u[2] = r0; pu.u[3] = r1; }
        else         { pu.u[0] = r0;    pu.u[1] = r1;    pu.u[2] = o0h.u; pu.u[3] = o1h.u; }
        pf[c] = pu.v8;
      }
      // ---- O^T += V^T . P^T  (V frags pipelined one dt ahead) ----
#pragma unroll
      for (int dt = 0; dt < 4; dt++) {
        f16x8 nf0, nf1;
        if (dt < 3) {
          const int vrow = (dt + 1) * 32 + l31;
          nf0 = *(const f16x8*)(VTlds + vrow * 64 +
                                (((sub * 4 + 0 * 2 + hf) ^ (vrow & 7)) << 3));
          nf1 = *(const f16x8*)(VTlds + vrow * 64 +
                                (((sub * 4 + 1 * 2 + hf) ^ (vrow & 7)) << 3));
        }
        __builtin_amdgcn_s_setprio(1);
        acc[dt] = __builtin_amdgcn_mfma_f32_32x32x16_f16(vf0, pf[0], acc[dt], 0, 0, 0);
        acc[dt] = __builtin_amdgcn_mfma_f32_32x32x16_f16(vf1, pf[1], acc[dt], 0, 0, 0);
        __builtin_amdgcn_s_setprio(0);
        vf0 = nf0; vf1 = nf1;
      }
    }
    __syncthreads();
  }

  // combine the two half-lane partial sums of l
  l_run += __shfl_xor(l_run, 32);
  const float f = vs / l_run;

  // ---- epilogue: stage fp16 in LDS, store FULL 256B lines (2 passes) ----
  // obuf: [4 waves][32 q][136 halves]; value at [q][dt*32+dl]
  _Float16* obuf = (_Float16*)ldsb;
  const int obase = wave * 4352;       // 32*136 halves
#pragma unroll
  for (int pass = 0; pass < 2; pass++) {
    __syncthreads();                   // K/V loop done / previous pass stored
#pragma unroll
    for (int dt = 0; dt < 4; dt++) {
#pragma unroll
      for (int iq = 0; iq < 4; iq++) { // i = iq*4 .. iq*4+3 -> dl0..dl0+3
        const int dl0 = 8 * iq + 4 * hf;
        H4b w;
#pragma unroll
        for (int e = 0; e < 4; e++) {
          const float o = acc[dt][iq * 4 + e] * f;
          const _Float16 hh = (_Float16)o;
          w.h[e] = pass ? (_Float16)(o - (float)hh) : hh;
        }
        *(uint2*)&obuf[obase + l31 * 136 + dt * 32 + dl0] = w.u2;
      }
    }
    __syncthreads();
    _Float16* dst = pass ? oLo : oHi;
#pragma unroll
    for (int ii = 0; ii < 8; ii++) {
      const int qrow = ii * 4 + (lane >> 4);
      const int ch = (lane & 15) * 8;  // halves within the 128-wide row
      uint4 val = *(const uint4*)&obuf[obase + qrow * 136 + ch];
      const size_t ofs = (size_t)(b * S_ + q0 + qrow) * H_ + h * HD + ch;
      *(uint4*)(dst + ofs) = val;
    }
  }
}

// ---------------------------------------------------------------------------
extern "C" void kernel_launch(void* const* d_in, const int* in_sizes, int n_in,
                              void* d_out, int out_size, void* d_ws, size_t ws_size,
                              hipStream_t stream) {
  const float* x     = (const float*)d_in[0];
  const float* W_qkv = (const float*)d_in[1];
  const float* W_out = (const float*)d_in[2];
  const float* b_out = (const float*)d_in[3];
  float* out = (float*)d_out;

  char* ws = (char*)d_ws;
  // Region 0 [0, 100.66 MB): qkv fp32; later A2 splits (attn output) + B2t
  float*    qkv    = (float*)ws;
  _Float16* A2hi   = (_Float16*)(ws + 33554432);               // 16,777,216 B
  _Float16* A2lo   = (_Float16*)(ws + 50331648);
  _Float16* B2thi  = (_Float16*)(ws + 67108864);               //  8,388,608 B
  _Float16* B2tlo  = (_Float16*)(ws + 75497472);
  // Region 1 [100.66, 151.0 MB): B1t splits, then reused for q8/k8/v8t
  _Float16* B1thi  = (_Float16*)(ws + 100663296);              // 25,165,824 B
  _Float16* B1tlo  = (_Float16*)(ws + 125829120);
  _Float16* q8     = (_Float16*)(ws + 100663296);              // 16,777,216 B
  _Float16* k8     = (_Float16*)(ws + 117440512);
  _Float16* v8t    = (_Float16*)(ws + 134217728);
  // Region 2 [151.0, 184.6 MB): A1 splits
  _Float16* A1hi   = (_Float16*)(ws + 150994944);
  _Float16* A1lo   = (_Float16*)(ws + 167772160);
  unsigned* mx     = (unsigned*)(ws + 184549376);

  hipMemsetAsync(mx, 0, 3 * sizeof(unsigned), stream);

  // fused prep: x -> A1 splits (8192 blocks) + W_qkv^T -> B1t (3072 blocks)
  prep_split<<<11264, 256, 0, stream>>>(x, W_qkv, A1hi, A1lo, B1thi, B1tlo);

  // qkv = x @ W_qkv  (split-fp16 MFMA, K' = 6144); 48x16 = 768 blocks
  // + fused per-segment max|qkv| -> mx
  gemm_split256<<<dim3(F3 / 128, ROWS / 256), 512, 0, stream>>>(
      A1hi, A1lo, B1thi, B1tlo, qkv, nullptr, mx, F3, 0);

  // fused quantization of Q,K (16384 blocks) and V-transposed (2048 blocks)
  quant_qkv<<<16384 + B_ * NH * 32 * 2, 256, 0, stream>>>(qkv, mx, q8, k8, v8t);

  // attention -> writes out-proj A-operand hi/lo directly
  attn_kernel<<<B_ * NH * 16, 256, 0, stream>>>(q8, k8, v8t, mx, A2hi, A2lo);

  // split W_out^T (B2t) — must follow quant_qkv (B2t aliases qkv region)
  split_tr<<<dim3(H_ / 64, H_ / 64), 256, 0, stream>>>(W_out, B2thi, B2tlo, H_, H_);

  // out = attn_out @ W_out + b_out; 16x16 = 256 blocks
  gemm_split256<<<dim3(H_ / 128, ROWS / 256), 512, 0, stream>>>(
      A2hi, A2lo, B2thi, B2tlo, out, b_out, nullptr, H_, 1);
}

// Round 13
// 718.329 us; speedup vs baseline: 1.0919x; 1.0919x over previous
//
#include <hip/hip_runtime.h>
#include <hip/hip_bf16.h>
#include <math.h>

#define B_   2
#define S_   2048
#define H_   2048
#define NH   16
#define HD   128
#define ROWS (B_ * S_)   // 4096
#define F3   (3 * H_)    // 6144
#define KS   2048        // inner dim of both projection GEMMs (per split term)

typedef _Float16 f16x8 __attribute__((ext_vector_type(8)));
typedef float    f32x4  __attribute__((ext_vector_type(4)));
typedef float    f32x16 __attribute__((ext_vector_type(16)));

union H2 { unsigned u; _Float16 h[2]; };
union H4 { ushort4 s4; _Float16 h[4]; };
union H4b { uint2 u2; _Float16 h[4]; };
union PU { unsigned u[4]; f16x8 v8; };

__device__ __forceinline__ void gl_lds16(const void* g, void* l) {
  __builtin_amdgcn_global_load_lds(
      (const __attribute__((address_space(1))) void*)g,
      (__attribute__((address_space(3))) void*)l, 16, 0, 0);
}

// ---------------------------------------------------------------------------
// fp8 e4m3fn RNE quantization -> representable value (exact in fp16)
// ---------------------------------------------------------------------------
__device__ __forceinline__ float quant_e4m3(float x) {
  float ax = fabsf(x);
  float q;
  if (ax < 0.015625f) {
    q = rintf(ax * 512.0f) * (1.0f / 512.0f);
  } else {
    unsigned eb = __float_as_uint(ax) & 0x7f800000u;
    float quantum = __uint_as_float(eb - (3u << 23));      // 2^(e-3)
    q = rintf(ax / quantum) * quantum;
    if (q > 448.0f) q = 448.0f;
  }
  return copysignf(q, x);
}

// ---------------------------------------------------------------------------
// Fused prep: blocks [0,8192) = x -> A1 hi/lo split (elementwise);
// blocks [8192,11264) = W_qkv -> B1t hi/lo split TRANSPOSED (n-tile,k-tile).
// ---------------------------------------------------------------------------
__global__ __launch_bounds__(256) void prep_split(
    const float* __restrict__ x, const float* __restrict__ Wqkv,
    _Float16* __restrict__ A1hi, _Float16* __restrict__ A1lo,
    _Float16* __restrict__ B1thi, _Float16* __restrict__ B1tlo) {
  __shared__ _Float16 ht[64][72];
  __shared__ _Float16 lt[64][72];
  const int t = threadIdx.x;
  const int bid = blockIdx.x;
  if (bid < 8192) {
    const size_t i = (size_t)bid * 256 + t;
    float4 v = ((const float4*)x)[i];
    H4 h, l;
    h.h[0] = (_Float16)v.x; l.h[0] = (_Float16)(v.x - (float)h.h[0]);
    h.h[1] = (_Float16)v.y; l.h[1] = (_Float16)(v.y - (float)h.h[1]);
    h.h[2] = (_Float16)v.z; l.h[2] = (_Float16)(v.z - (float)h.h[2]);
    h.h[3] = (_Float16)v.w; l.h[3] = (_Float16)(v.w - (float)h.h[3]);
    ((ushort4*)A1hi)[i] = h.s4;
    ((ushort4*)A1lo)[i] = l.s4;
  } else {
    const int idx = bid - 8192;            // 0..3071
    const int n0 = (idx % 96) * 64, k0 = (idx / 96) * 64;
    const int K = H_, N = F3;
#pragma unroll
    for (int p = 0; p < 4; p++) {
      const int k = p * 16 + (t >> 4);
      const int n = (t & 15) * 4;
      float4 v = *(const float4*)(Wqkv + (size_t)(k0 + k) * N + n0 + n);
      _Float16 h0 = (_Float16)v.x, h1 = (_Float16)v.y,
               h2 = (_Float16)v.z, h3 = (_Float16)v.w;
      ht[n + 0][k] = h0; lt[n + 0][k] = (_Float16)(v.x - (float)h0);
      ht[n + 1][k] = h1; lt[n + 1][k] = (_Float16)(v.y - (float)h1);
      ht[n + 2][k] = h2; lt[n + 2][k] = (_Float16)(v.z - (float)h2);
      ht[n + 3][k] = h3; lt[n + 3][k] = (_Float16)(v.w - (float)h3);
    }
    __syncthreads();
#pragma unroll
    for (int it = 0; it < 2; it++) {
      const int idx2 = it * 256 + t;
      const int r = idx2 >> 3, c = (idx2 & 7) * 8;
      *(uint4*)(B1thi + (size_t)(n0 + r) * K + k0 + c) = *(const uint4*)&ht[r][c];
      *(uint4*)(B1tlo + (size_t)(n0 + r) * K + k0 + c) = *(const uint4*)&lt[r][c];
    }
  }
}

// ---------------------------------------------------------------------------
// fp32 K x N -> fp16 hi/lo, TRANSPOSED to N x K (kept for W_out)
// ---------------------------------------------------------------------------
__global__ __launch_bounds__(256) void split_tr(
    const float* __restrict__ in, _Float16* __restrict__ hi,
    _Float16* __restrict__ lo, int K, int N) {
  __shared__ _Float16 ht[64][72];
  __shared__ _Float16 lt[64][72];
  const int t = threadIdx.x;
  const int n0 = blockIdx.x * 64, k0 = blockIdx.y * 64;
#pragma unroll
  for (int p = 0; p < 4; p++) {
    const int k = p * 16 + (t >> 4);
    const int n = (t & 15) * 4;
    float4 v = *(const float4*)(in + (size_t)(k0 + k) * N + n0 + n);
    _Float16 h0 = (_Float16)v.x, h1 = (_Float16)v.y,
             h2 = (_Float16)v.z, h3 = (_Float16)v.w;
    ht[n + 0][k] = h0; lt[n + 0][k] = (_Float16)(v.x - (float)h0);
    ht[n + 1][k] = h1; lt[n + 1][k] = (_Float16)(v.y - (float)h1);
    ht[n + 2][k] = h2; lt[n + 2][k] = (_Float16)(v.z - (float)h2);
    ht[n + 3][k] = h3; lt[n + 3][k] = (_Float16)(v.w - (float)h3);
  }
  __syncthreads();
#pragma unroll
  for (int it = 0; it < 2; it++) {
    const int idx = it * 256 + t;
    const int r = idx >> 3, c = (idx & 7) * 8;
    *(uint4*)(hi + (size_t)(n0 + r) * K + k0 + c) = *(const uint4*)&ht[r][c];
    *(uint4*)(lo + (size_t)(n0 + r) * K + k0 + c) = *(const uint4*)&lt[r][c];
  }
}

// ---------------------------------------------------------------------------
// MFMA split-fp16 GEMM — round-7/11 triple-buffer body REVERTED verbatim
// (measured plateau: G1 = 299.5 us, MfmaUtil 48, 0 conflicts). Three
// pipelining grafts (BK=32 4-buf, frag-dbuf, phase-split) all regressed;
// this structure is declared at its plateau. Fused max|C| epilogue kept.
// ---------------------------------------------------------------------------
#define STAGE_A(tt, dst) do {                                                  \
    const _Float16* As_ = ((tt) < 64) ? Ahi : Alo;                             \
    const size_t so_ = (size_t)(row0 + wave * 8 + srow) * KS +                 \
                       (((tt) & 31) << 6) + schunk;                            \
    _Float16* db_ = (dst) + wave * 512;                                        \
    gl_lds16(As_ + so_,                    db_);                               \
    gl_lds16(As_ + so_ + (size_t)64 * KS,  db_ + 4096);                        \
    gl_lds16(As_ + so_ + (size_t)128 * KS, db_ + 8192);                       \
    gl_lds16(As_ + so_ + (size_t)192 * KS, db_ + 12288);                       \
  } while (0)

#define STAGE_B(tt, dst) do {                                                  \
    const _Float16* Bs_ = ((((tt) >> 5)) == 1) ? Btlo : Bthi;                  \
    const size_t so_ = (size_t)(col0 + wave * 8 + srow) * KS +                 \
                       (((tt) & 31) << 6) + schunk;                            \
    _Float16* db_ = (dst) + 16384 + wave * 512;                                \
    gl_lds16(Bs_ + so_,                    db_);                               \
    gl_lds16(Bs_ + so_ + (size_t)64 * KS,  db_ + 4096);                        \
  } while (0)

__global__ __launch_bounds__(512, 2) void gemm_split256(
    const _Float16* __restrict__ Ahi, const _Float16* __restrict__ Alo,
    const _Float16* __restrict__ Bthi, const _Float16* __restrict__ Btlo,
    float* __restrict__ C, const float* __restrict__ bias,
    unsigned* mx, int N, int has_bias) {
  __shared__ __align__(16) _Float16 lds[73728];   // 3 x 48 KiB = 144 KiB
  const int t = threadIdx.x;
  const int wave = t >> 6, lane = t & 63;
  const int l15 = lane & 15, g = lane >> 4;
  const int wm = wave >> 1, wn = wave & 1;    // 4M x 2N wave grid

  // XCD-aware bijective tile swizzle (both grids are multiples of 8)
  const int gx = gridDim.x;
  const int nwg = gx * gridDim.y;
  const int bid = blockIdx.y * gx + blockIdx.x;
  const int tile = (bid & 7) * (nwg >> 3) + (bid >> 3);
  const int row0 = (tile / gx) * 256, col0 = (tile % gx) * 128;

  // staging coords: 8 rows x 128B per wave per load; source chunk XOR-swizzled
  const int srow = lane >> 3;                    // row&7 of staged row
  const int schunk = ((lane & 7) ^ srow) << 3;   // halves

  f32x4 acc[4][4] = {};

  _Float16* bufA = lds;                 // tile kc   (compute)
  _Float16* bufB = lds + 24576;         // tile kc+1 (in flight / landed)
  _Float16* bufC = lds + 49152;         // tile kc+2 (stage target)

  // prologue: tile0 -> bufA, tile1 -> bufB; retire tile0 (6), keep tile1 flying
  STAGE_A(0, bufA);
  STAGE_B(0, bufA);
  STAGE_A(1, bufB);
  STAGE_B(1, bufB);
  asm volatile("s_waitcnt vmcnt(6)" ::: "memory");
  __builtin_amdgcn_s_barrier();

  for (int kc = 0; kc < 96; kc++) {
    const _Float16* Ab = bufA;
    const _Float16* Bb = bufA + 16384;
    f16x8 af0[4], bf0[4], af1[4], bf1[4];
#pragma unroll
    for (int i = 0; i < 4; i++) {
      const int r_ = wm * 64 + i * 16 + l15;
      af0[i] = *(const f16x8*)(Ab + r_ * 64 + ((g ^ (r_ & 7)) << 3));
      af1[i] = *(const f16x8*)(Ab + r_ * 64 + (((4 ^ g) ^ (r_ & 7)) << 3));
    }
#pragma unroll
    for (int j = 0; j < 4; j++) {
      const int r_ = wn * 64 + j * 16 + l15;
      bf0[j] = *(const f16x8*)(Bb + r_ * 64 + ((g ^ (r_ & 7)) << 3));
      bf1[j] = *(const f16x8*)(Bb + r_ * 64 + (((4 ^ g) ^ (r_ & 7)) << 3));
    }
    // stage tile kc+2 into the buffer freed at the end of kc-1
    if (kc + 2 < 96) {
      STAGE_A(kc + 2, bufC);
      STAGE_B(kc + 2, bufC);
    }
    // k-half 0 then k-half 1 (accumulation order identical to prior rounds)
#pragma unroll
    for (int i = 0; i < 4; i++)
#pragma unroll
      for (int j = 0; j < 4; j++)
        acc[i][j] = __builtin_amdgcn_mfma_f32_16x16x32_f16(af0[i], bf0[j], acc[i][j], 0, 0, 0);
#pragma unroll
    for (int i = 0; i < 4; i++)
#pragma unroll
      for (int j = 0; j < 4; j++)
        acc[i][j] = __builtin_amdgcn_mfma_f32_16x16x32_f16(af1[i], bf1[j], acc[i][j], 0, 0, 0);
    // retire tile kc+1's 6 loads; keep tile kc+2's 6 in flight
    if (kc < 94) { asm volatile("s_waitcnt vmcnt(6)" ::: "memory"); }
    else         { asm volatile("s_waitcnt vmcnt(0)" ::: "memory"); }
    __builtin_amdgcn_s_barrier();
    _Float16* tmp = bufA; bufA = bufB; bufB = bufC; bufC = tmp;
  }

  float bmax = 0.0f;
#pragma unroll
  for (int j = 0; j < 4; j++) {
    const int col = col0 + wn * 64 + j * 16 + l15;
    const float bv = has_bias ? bias[col] : 0.0f;
#pragma unroll
    for (int i = 0; i < 4; i++) {
      const int rbase = row0 + wm * 64 + i * 16 + g * 4;
#pragma unroll
      for (int r = 0; r < 4; r++) {
        const float v = acc[i][j][r] + bv;
        C[(size_t)(rbase + r) * N + col] = v;
        bmax = fmaxf(bmax, fabsf(v));
      }
    }
  }

  // fused per-segment max|.| (gemm1 only): block lies wholly in segment col0>>11
  if (mx) {
    __syncthreads();                 // K-loop done; LDS free for reduction
    float* red = (float*)lds;
    red[t] = bmax;
    __syncthreads();
    for (int s2 = 256; s2 > 0; s2 >>= 1) {
      if (t < s2) red[t] = fmaxf(red[t], red[t + s2]);
      __syncthreads();
    }
    if (t == 0) atomicMax(mx + (col0 >> 11), __float_as_uint(red[0]));
  }
}

// ---------------------------------------------------------------------------
// Fused quantization: Q,K segments -> q8/k8 [bh][s][d]; V -> v8t[bh][d][s]
// ---------------------------------------------------------------------------
__global__ __launch_bounds__(256) void quant_qkv(
    const float* __restrict__ qkv, const unsigned* __restrict__ mx,
    _Float16* __restrict__ q8, _Float16* __restrict__ k8,
    _Float16* __restrict__ v8t) {
  __shared__ _Float16 tile[64 * 72];
  const int t = threadIdx.x;
  const int bid = blockIdx.x;

  if (bid < 16384) {
    // ---- Q/K path ----
    const size_t base = ((size_t)bid * 256 + t) * 4;
    const int row = (int)(base >> 12);
    const int col = (int)(base & 4095);
    const int seg = col >> 11;
    const int c2 = col & 2047;
    const int h = c2 >> 7, d = c2 & 127;
    const int b = row >> 11, s = row & 2047;
    const float scale = __uint_as_float(mx[seg]) / 448.0f;
    float4 v = *(const float4*)(qkv + (size_t)row * F3 + col);
    H4 r;
    r.h[0] = (_Float16)quant_e4m3(v.x / scale);
    r.h[1] = (_Float16)quant_e4m3(v.y / scale);
    r.h[2] = (_Float16)quant_e4m3(v.z / scale);
    r.h[3] = (_Float16)quant_e4m3(v.w / scale);
    _Float16* dst = seg ? k8 : q8;
    const size_t di = ((size_t)((b * NH + h) * S_) + s) * HD + d;
    *(ushort4*)(dst + di) = r.s4;
  } else {
    // ---- V path (transposed store) ----
    const int bt = bid - 16384;
    const int dtile = bt & 1;
    const int stile = (bt >> 1) & 31;
    const int bh = bt >> 6;
    const int b = bh >> 4, h = bh & 15;
    const int s0 = stile * 64, d0 = dtile * 64;
    const float scale = __uint_as_float(mx[2]) / 448.0f;

#pragma unroll
    for (int r = 0; r < 4; r++) {
      const int s = s0 + r * 16 + (t >> 4);
      const int dl = (t & 15) * 4;
      float4 v = *(const float4*)(qkv + (size_t)(b * S_ + s) * F3 + 4096 + h * HD + d0 + dl);
      tile[(dl + 0) * 72 + r * 16 + (t >> 4)] = (_Float16)quant_e4m3(v.x / scale);
      tile[(dl + 1) * 72 + r * 16 + (t >> 4)] = (_Float16)quant_e4m3(v.y / scale);
      tile[(dl + 2) * 72 + r * 16 + (t >> 4)] = (_Float16)quant_e4m3(v.z / scale);
      tile[(dl + 3) * 72 + r * 16 + (t >> 4)] = (_Float16)quant_e4m3(v.w / scale);
    }
    __syncthreads();
#pragma unroll
    for (int j = 0; j < 2; j++) {
      const int wi = j * 256 + t;
      const int dl = wi >> 3;
      const int sch = (wi & 7) * 8;
      uint4 val = *(const uint4*)(tile + dl * 72 + sch);
      *(uint4*)(v8t + (size_t)bh * (HD * S_) + (size_t)(d0 + dl) * S_ + s0 + sch) = val;
    }
  }
}

// ---------------------------------------------------------------------------
// MFMA flash attention, round-17: per kt, sub0/sub1 QK^T chains are computed
// as TWO INTERLEAVED independent MFMA chains (2-way ILP -> chain latency
// halved; the old code ran them back-to-back, each an 8-deep serial chain
// into one accumulator). Softmax/pack for both, then PV ordered
// for dt {sub0:c0,c1; sub1:c0,c1} — identical per-accumulator order to the
// original for sub {for dt {for c}}; l_run order rs0-then-rs1 preserved;
// m_base logic preserved -> bit-identical output. Staging + epilogue
// unchanged from round 15.
// ---------------------------------------------------------------------------
__global__ __launch_bounds__(256, 2) void attn_kernel(
    const _Float16* __restrict__ q8, const _Float16* __restrict__ k8,
    const _Float16* __restrict__ v8t, const unsigned* __restrict__ mx,
    _Float16* __restrict__ oHi, _Float16* __restrict__ oLo) {
  __shared__ __align__(16) char ldsb[65536];
  // K buffers: ldsb + {0, 16384}   : [64 keys][128 halves], chunk^=(row&7)
  // V buffers: ldsb + {32768, 49152}: [128 d][64 halves],   chunk^=(row&7)

  const int t = threadIdx.x;        // 0..255
  const int wave = t >> 6;          // 0..3
  const int lane = t & 63;
  const int l31 = lane & 31;
  const int hf = lane >> 5;

  const int qt = blockIdx.x & 15;
  const int bh = blockIdx.x >> 4;
  const int b = bh >> 4, h = bh & 15;
  const int q0 = qt * 128 + wave * 32;   // this wave's 32 queries

  const float qs = __uint_as_float(mx[0]) * (1.0f / 448.0f);
  const float ks = __uint_as_float(mx[1]) * (1.0f / 448.0f);
  const float vs = __uint_as_float(mx[2]) * (1.0f / 448.0f);
  const float sfac = qs * ks * 0.08838834764831843f;   // 1/sqrt(128)

  // Q fragments (B-layout): Q[q=l31][d = st*16 + hf*8 + j]
  f16x8 qf[8];
  {
    const _Float16* qp = q8 + ((size_t)(bh * S_) + q0 + l31) * HD + hf * 8;
#pragma unroll
    for (int st = 0; st < 8; st++)
      qf[st] = *(const f16x8*)(qp + st * 16);
  }

  f32x16 acc[4] = {};
  float m_base = 0.0f;
  float l_run = 0.0f;

  const size_t kB_ = (size_t)(bh * S_) * HD;
  const size_t vB_ = (size_t)bh * (HD * S_);
  // per-thread staging coordinates
  const int k_key = t >> 4;            // + r*16 ; row&7 = k_key&7
  const int k_dch = (t & 15) * 8;      // global chunk offset (halves)
  const int k_wch = (((t & 15) ^ (k_key & 7)) << 3);   // swizzled LDS chunk
  const int v_d   = t >> 3;            // + r*32 ; row&7 = v_d&7
  const int v_sch = (t & 7) * 8;       // global chunk offset (halves)
  const int v_wch = (((t & 7) ^ (v_d & 7)) << 3);      // swizzled LDS chunk

  const int NT = S_ / 64;              // 32
  uint4 kp[4], vp[4];

  // prologue: load tile 0, write -> buffers[0], issue tile 1 loads, barrier
#pragma unroll
  for (int r = 0; r < 4; r++)
    kp[r] = *(const uint4*)(k8 + kB_ + (size_t)(r * 16 + k_key) * HD + k_dch);
#pragma unroll
  for (int r = 0; r < 4; r++)
    vp[r] = *(const uint4*)(v8t + vB_ + (size_t)(r * 32 + v_d) * S_ + v_sch);
  {
    _Float16* K0 = (_Float16*)ldsb;
    _Float16* V0 = (_Float16*)(ldsb + 32768);
#pragma unroll
    for (int r = 0; r < 4; r++)
      *(uint4*)(K0 + (r * 16 + k_key) * 128 + k_wch) = kp[r];
#pragma unroll
    for (int r = 0; r < 4; r++)
      *(uint4*)(V0 + (r * 32 + v_d) * 64 + v_wch) = vp[r];
  }
#pragma unroll
  for (int r = 0; r < 4; r++)
    kp[r] = *(const uint4*)(k8 + kB_ + (size_t)(64 + r * 16 + k_key) * HD + k_dch);
#pragma unroll
  for (int r = 0; r < 4; r++)
    vp[r] = *(const uint4*)(v8t + vB_ + (size_t)(r * 32 + v_d) * S_ + 64 + v_sch);
  __syncthreads();

  for (int kt = 0; kt < NT; kt++) {
    const _Float16* Klds  = (const _Float16*)(ldsb + (kt & 1) * 16384);
    const _Float16* VTlds = (const _Float16*)(ldsb + 32768 + (kt & 1) * 16384);
    // write tile kt+1 (in kp/vp) into the other buffer; overlaps compute
    if (kt + 1 < NT) {
      _Float16* Kn = (_Float16*)(ldsb + ((kt + 1) & 1) * 16384);
      _Float16* Vn = (_Float16*)(ldsb + 32768 + ((kt + 1) & 1) * 16384);
#pragma unroll
      for (int r = 0; r < 4; r++)
        *(uint4*)(Kn + (r * 16 + k_key) * 128 + k_wch) = kp[r];
#pragma unroll
      for (int r = 0; r < 4; r++)
        *(uint4*)(Vn + (r * 32 + v_d) * 64 + v_wch) = vp[r];
    }
    // issue tile kt+2's global loads (consumed next iteration)
    if (kt + 2 < NT) {
      const int nk = (kt + 2) * 64;
#pragma unroll
      for (int r = 0; r < 4; r++)
        kp[r] = *(const uint4*)(k8 + kB_ + (size_t)(nk + r * 16 + k_key) * HD + k_dch);
#pragma unroll
      for (int r = 0; r < 4; r++)
        vp[r] = *(const uint4*)(v8t + vB_ + (size_t)(r * 32 + v_d) * S_ + nk + v_sch);
    }

    // ---- S^T = K . Q^T for BOTH 32-key sub-tiles: two interleaved chains ----
    f32x16 s0 = {}, s1 = {};
    __builtin_amdgcn_s_setprio(1);
#pragma unroll
    for (int st = 0; st < 8; st++) {
      const int kr0 = l31;
      const int kr1 = 32 + l31;
      f16x8 a0 = *(const f16x8*)(Klds + kr0 * 128 +
                                 (((st * 2 + hf) ^ (kr0 & 7)) << 3));
      f16x8 a1 = *(const f16x8*)(Klds + kr1 * 128 +
                                 (((st * 2 + hf) ^ (kr1 & 7)) << 3));
      s0 = __builtin_amdgcn_mfma_f32_32x32x16_f16(a0, qf[st], s0, 0, 0, 0);
      s1 = __builtin_amdgcn_mfma_f32_32x32x16_f16(a1, qf[st], s1, 0, 0, 0);
    }
    __builtin_amdgcn_s_setprio(0);

    // prefetch dt=0 V fragments for both subs (latency hides under softmax)
    f16x8 vf00 = *(const f16x8*)(VTlds + l31 * 64 + (((0 + hf) ^ (l31 & 7)) << 3));
    f16x8 vf01 = *(const f16x8*)(VTlds + l31 * 64 + (((2 + hf) ^ (l31 & 7)) << 3));
    f16x8 vf10 = *(const f16x8*)(VTlds + l31 * 64 + (((4 + hf) ^ (l31 & 7)) << 3));
    f16x8 vf11 = *(const f16x8*)(VTlds + l31 * 64 + (((6 + hf) ^ (l31 & 7)) << 3));

    // ---- fixed-base softmax weights (sub0 then sub1; order preserved) ----
    float p0[16], p1[16];
    if (kt == 0) {
      float tmax = -3.0e38f;
#pragma unroll
      for (int i = 0; i < 16; i++) {
        p0[i] = s0[i] * sfac;
        tmax = fmaxf(tmax, p0[i]);
      }
      tmax = fmaxf(tmax, __shfl_xor(tmax, 32));
      m_base = tmax;
      float rs = 0.0f;
#pragma unroll
      for (int i = 0; i < 16; i++) {
        p0[i] = __expf(p0[i] - tmax);
        rs += p0[i];
      }
      l_run += rs;
    } else {
      const float mb = m_base;
      float rs = 0.0f;
#pragma unroll
      for (int i = 0; i < 16; i++) {
        p0[i] = fminf(__expf(fmaf(s0[i], sfac, -mb)), 60000.0f);
        rs += p0[i];
      }
      l_run += rs;
    }
    {
      const float mb = m_base;
      float rs = 0.0f;
#pragma unroll
      for (int i = 0; i < 16; i++) {
        p1[i] = fminf(__expf(fmaf(s1[i], sfac, -mb)), 60000.0f);
        rs += p1[i];
      }
      l_run += rs;
    }

    // ---- pack + cross-half exchange -> P^T B-frags (both subs) ----
    f16x8 pf0[2], pf1[2];
#pragma unroll
    for (int sb = 0; sb < 2; sb++) {
      const float* pp = sb ? p1 : p0;
      f16x8* pf = sb ? pf1 : pf0;
#pragma unroll
      for (int c = 0; c < 2; c++) {
        const int c8 = c * 8;
        const int sidx = hf ? 0 : 4;
        const int oidx = hf ? 4 : 0;
        H2 s0h, s1h, o0h, o1h;
        s0h.h[0] = (_Float16)pp[c8 + sidx];     s0h.h[1] = (_Float16)pp[c8 + sidx + 1];
        s1h.h[0] = (_Float16)pp[c8 + sidx + 2]; s1h.h[1] = (_Float16)pp[c8 + sidx + 3];
        o0h.h[0] = (_Float16)pp[c8 + oidx];     o0h.h[1] = (_Float16)pp[c8 + oidx + 1];
        o1h.h[0] = (_Float16)pp[c8 + oidx + 2]; o1h.h[1] = (_Float16)pp[c8 + oidx + 3];
        unsigned r0 = (unsigned)__shfl_xor((int)s0h.u, 32);
        unsigned r1 = (unsigned)__shfl_xor((int)s1h.u, 32);
        PU pu;
        if (hf == 0) { pu.u[0] = o0h.u; pu.u[1] = o1h.u; pu.u[2] = r0; pu.u[3] = r1; }
        else         { pu.u[0] = r0;    pu.u[1] = r1;    pu.u[2] = o0h.u; pu.u[3] = o1h.u; }
        pf[c] = pu.v8;
      }
    }

    // ---- O^T += V^T . P^T  (per-acc order: sub0 c0,c1 then sub1 c0,c1) ----
#pragma unroll
    for (int dt = 0; dt < 4; dt++) {
      f16x8 n00, n01, n10, n11;
      if (dt < 3) {
        const int vrow = (dt + 1) * 32 + l31;
        n00 = *(const f16x8*)(VTlds + vrow * 64 + (((0 + hf) ^ (vrow & 7)) << 3));
        n01 = *(const f16x8*)(VTlds + vrow * 64 + (((2 + hf) ^ (vrow & 7)) << 3));
        n10 = *(const f16x8*)(VTlds + vrow * 64 + (((4 + hf) ^ (vrow & 7)) << 3));
        n11 = *(const f16x8*)(VTlds + vrow * 64 + (((6 + hf) ^ (vrow & 7)) << 3));
      }
      __builtin_amdgcn_s_setprio(1);
      acc[dt] = __builtin_amdgcn_mfma_f32_32x32x16_f16(vf00, pf0[0], acc[dt], 0, 0, 0);
      acc[dt] = __builtin_amdgcn_mfma_f32_32x32x16_f16(vf01, pf0[1], acc[dt], 0, 0, 0);
      acc[dt] = __builtin_amdgcn_mfma_f32_32x32x16_f16(vf10, pf1[0], acc[dt], 0, 0, 0);
      acc[dt] = __builtin_amdgcn_mfma_f32_32x32x16_f16(vf11, pf1[1], acc[dt], 0, 0, 0);
      __builtin_amdgcn_s_setprio(0);
      vf00 = n00; vf01 = n01; vf10 = n10; vf11 = n11;
    }
    __syncthreads();
  }

  // combine the two half-lane partial sums of l
  l_run += __shfl_xor(l_run, 32);
  const float f = vs / l_run;

  // ---- epilogue: stage fp16 in LDS, store FULL 256B lines (2 passes) ----
  // obuf: [4 waves][32 q][136 halves]; value at [q][dt*32+dl]
  _Float16* obuf = (_Float16*)ldsb;
  const int obase = wave * 4352;       // 32*136 halves
#pragma unroll
  for (int pass = 0; pass < 2; pass++) {
    __syncthreads();                   // K/V loop done / previous pass stored
#pragma unroll
    for (int dt = 0; dt < 4; dt++) {
#pragma unroll
      for (int iq = 0; iq < 4; iq++) { // i = iq*4 .. iq*4+3 -> dl0..dl0+3
        const int dl0 = 8 * iq + 4 * hf;
        H4b w;
#pragma unroll
        for (int e = 0; e < 4; e++) {
          const float o = acc[dt][iq * 4 + e] * f;
          const _Float16 hh = (_Float16)o;
          w.h[e] = pass ? (_Float16)(o - (float)hh) : hh;
        }
        *(uint2*)&obuf[obase + l31 * 136 + dt * 32 + dl0] = w.u2;
      }
    }
    __syncthreads();
    _Float16* dst = pass ? oLo : oHi;
#pragma unroll
    for (int ii = 0; ii < 8; ii++) {
      const int qrow = ii * 4 + (lane >> 4);
      const int ch = (lane & 15) * 8;  // halves within the 128-wide row
      uint4 val = *(const uint4*)&obuf[obase + qrow * 136 + ch];
      const size_t ofs = (size_t)(b * S_ + q0 + qrow) * H_ + h * HD + ch;
      *(uint4*)(dst + ofs) = val;
    }
  }
}

// ---------------------------------------------------------------------------
extern "C" void kernel_launch(void* const* d_in, const int* in_sizes, int n_in,
                              void* d_out, int out_size, void* d_ws, size_t ws_size,
                              hipStream_t stream) {
  const float* x     = (const float*)d_in[0];
  const float* W_qkv = (const float*)d_in[1];
  const float* W_out = (const float*)d_in[2];
  const float* b_out = (const float*)d_in[3];
  float* out = (float*)d_out;

  char* ws = (char*)d_ws;
  // Region 0 [0, 100.66 MB): qkv fp32; later A2 splits (attn output) + B2t
  float*    qkv    = (float*)ws;
  _Float16* A2hi   = (_Float16*)(ws + 33554432);               // 16,777,216 B
  _Float16* A2lo   = (_Float16*)(ws + 50331648);
  _Float16* B2thi  = (_Float16*)(ws + 67108864);               //  8,388,608 B
  _Float16* B2tlo  = (_Float16*)(ws + 75497472);
  // Region 1 [100.66, 151.0 MB): B1t splits, then reused for q8/k8/v8t
  _Float16* B1thi  = (_Float16*)(ws + 100663296);              // 25,165,824 B
  _Float16* B1tlo  = (_Float16*)(ws + 125829120);
  _Float16* q8     = (_Float16*)(ws + 100663296);              // 16,777,216 B
  _Float16* k8     = (_Float16*)(ws + 117440512);
  _Float16* v8t    = (_Float16*)(ws + 134217728);
  // Region 2 [151.0, 184.6 MB): A1 splits
  _Float16* A1hi   = (_Float16*)(ws + 150994944);
  _Float16* A1lo   = (_Float16*)(ws + 167772160);
  unsigned* mx     = (unsigned*)(ws + 184549376);

  hipMemsetAsync(mx, 0, 3 * sizeof(unsigned), stream);

  // fused prep: x -> A1 splits (8192 blocks) + W_qkv^T -> B1t (3072 blocks)
  prep_split<<<11264, 256, 0, stream>>>(x, W_qkv, A1hi, A1lo, B1thi, B1tlo);

  // qkv = x @ W_qkv  (split-fp16 MFMA, K' = 6144); 48x16 = 768 blocks
  // + fused per-segment max|qkv| -> mx
  gemm_split256<<<dim3(F3 / 128, ROWS / 256), 512, 0, stream>>>(
      A1hi, A1lo, B1thi, B1tlo, qkv, nullptr, mx, F3, 0);

  // fused quantization of Q,K (16384 blocks) and V-transposed (2048 blocks)
  quant_qkv<<<16384 + B_ * NH * 32 * 2, 256, 0, stream>>>(qkv, mx, q8, k8, v8t);

  // attention -> writes out-proj A-operand hi/lo directly
  attn_kernel<<<B_ * NH * 16, 256, 0, stream>>>(q8, k8, v8t, mx, A2hi, A2lo);

  // split W_out^T (B2t) — must follow quant_qkv (B2t aliases qkv region)
  split_tr<<<dim3(H_ / 64, H_ / 64), 256, 0, stream>>>(W_out, B2thi, B2tlo, H_, H_);

  // out = attn_out @ W_out + b_out; 16x16 = 256 blocks
  gemm_split256<<<dim3(H_ / 128, ROWS / 256), 512, 0, stream>>>(
      A2hi, A2lo, B2thi, B2tlo, out, b_out, nullptr, H_, 1);
}

// Round 14
// 699.687 us; speedup vs baseline: 1.1210x; 1.0266x over previous
//
#include <hip/hip_runtime.h>
#include <hip/hip_bf16.h>
#include <math.h>

#define B_   2
#define S_   2048
#define H_   2048
#define NH   16
#define HD   128
#define ROWS (B_ * S_)   // 4096
#define F3   (3 * H_)    // 6144
#define KS   2048        // inner dim of both projection GEMMs (per split term)

typedef _Float16 f16x8 __attribute__((ext_vector_type(8)));
typedef float    f32x4  __attribute__((ext_vector_type(4)));
typedef float    f32x16 __attribute__((ext_vector_type(16)));

union H2 { unsigned u; _Float16 h[2]; };
union H4 { ushort4 s4; _Float16 h[4]; };
union H4b { uint2 u2; _Float16 h[4]; };
union PU { unsigned u[4]; f16x8 v8; };

__device__ __forceinline__ void gl_lds16(const void* g, void* l) {
  __builtin_amdgcn_global_load_lds(
      (const __attribute__((address_space(1))) void*)g,
      (__attribute__((address_space(3))) void*)l, 16, 0, 0);
}

// ---------------------------------------------------------------------------
// fp8 e4m3fn RNE quantization -> representable value (exact in fp16)
// ---------------------------------------------------------------------------
__device__ __forceinline__ float quant_e4m3(float x) {
  float ax = fabsf(x);
  float q;
  if (ax < 0.015625f) {
    q = rintf(ax * 512.0f) * (1.0f / 512.0f);
  } else {
    unsigned eb = __float_as_uint(ax) & 0x7f800000u;
    float quantum = __uint_as_float(eb - (3u << 23));      // 2^(e-3)
    q = rintf(ax / quantum) * quantum;
    if (q > 448.0f) q = 448.0f;
  }
  return copysignf(q, x);
}

// ---------------------------------------------------------------------------
// Fused prep: blocks [0,8192) = x -> A1 hi/lo split (elementwise);
// blocks [8192,11264) = W_qkv -> B1t hi/lo split TRANSPOSED (n-tile,k-tile).
// ---------------------------------------------------------------------------
__global__ __launch_bounds__(256) void prep_split(
    const float* __restrict__ x, const float* __restrict__ Wqkv,
    _Float16* __restrict__ A1hi, _Float16* __restrict__ A1lo,
    _Float16* __restrict__ B1thi, _Float16* __restrict__ B1tlo) {
  __shared__ _Float16 ht[64][72];
  __shared__ _Float16 lt[64][72];
  const int t = threadIdx.x;
  const int bid = blockIdx.x;
  if (bid < 8192) {
    const size_t i = (size_t)bid * 256 + t;
    float4 v = ((const float4*)x)[i];
    H4 h, l;
    h.h[0] = (_Float16)v.x; l.h[0] = (_Float16)(v.x - (float)h.h[0]);
    h.h[1] = (_Float16)v.y; l.h[1] = (_Float16)(v.y - (float)h.h[1]);
    h.h[2] = (_Float16)v.z; l.h[2] = (_Float16)(v.z - (float)h.h[2]);
    h.h[3] = (_Float16)v.w; l.h[3] = (_Float16)(v.w - (float)h.h[3]);
    ((ushort4*)A1hi)[i] = h.s4;
    ((ushort4*)A1lo)[i] = l.s4;
  } else {
    const int idx = bid - 8192;            // 0..3071
    const int n0 = (idx % 96) * 64, k0 = (idx / 96) * 64;
    const int K = H_, N = F3;
#pragma unroll
    for (int p = 0; p < 4; p++) {
      const int k = p * 16 + (t >> 4);
      const int n = (t & 15) * 4;
      float4 v = *(const float4*)(Wqkv + (size_t)(k0 + k) * N + n0 + n);
      _Float16 h0 = (_Float16)v.x, h1 = (_Float16)v.y,
               h2 = (_Float16)v.z, h3 = (_Float16)v.w;
      ht[n + 0][k] = h0; lt[n + 0][k] = (_Float16)(v.x - (float)h0);
      ht[n + 1][k] = h1; lt[n + 1][k] = (_Float16)(v.y - (float)h1);
      ht[n + 2][k] = h2; lt[n + 2][k] = (_Float16)(v.z - (float)h2);
      ht[n + 3][k] = h3; lt[n + 3][k] = (_Float16)(v.w - (float)h3);
    }
    __syncthreads();
#pragma unroll
    for (int it = 0; it < 2; it++) {
      const int idx2 = it * 256 + t;
      const int r = idx2 >> 3, c = (idx2 & 7) * 8;
      *(uint4*)(B1thi + (size_t)(n0 + r) * K + k0 + c) = *(const uint4*)&ht[r][c];
      *(uint4*)(B1tlo + (size_t)(n0 + r) * K + k0 + c) = *(const uint4*)&lt[r][c];
    }
  }
}

// ---------------------------------------------------------------------------
// fp32 K x N -> fp16 hi/lo, TRANSPOSED to N x K (kept for W_out)
// ---------------------------------------------------------------------------
__global__ __launch_bounds__(256) void split_tr(
    const float* __restrict__ in, _Float16* __restrict__ hi,
    _Float16* __restrict__ lo, int K, int N) {
  __shared__ _Float16 ht[64][72];
  __shared__ _Float16 lt[64][72];
  const int t = threadIdx.x;
  const int n0 = blockIdx.x * 64, k0 = blockIdx.y * 64;
#pragma unroll
  for (int p = 0; p < 4; p++) {
    const int k = p * 16 + (t >> 4);
    const int n = (t & 15) * 4;
    float4 v = *(const float4*)(in + (size_t)(k0 + k) * N + n0 + n);
    _Float16 h0 = (_Float16)v.x, h1 = (_Float16)v.y,
             h2 = (_Float16)v.z, h3 = (_Float16)v.w;
    ht[n + 0][k] = h0; lt[n + 0][k] = (_Float16)(v.x - (float)h0);
    ht[n + 1][k] = h1; lt[n + 1][k] = (_Float16)(v.y - (float)h1);
    ht[n + 2][k] = h2; lt[n + 2][k] = (_Float16)(v.z - (float)h2);
    ht[n + 3][k] = h3; lt[n + 3][k] = (_Float16)(v.w - (float)h3);
  }
  __syncthreads();
#pragma unroll
  for (int it = 0; it < 2; it++) {
    const int idx = it * 256 + t;
    const int r = idx >> 3, c = (idx & 7) * 8;
    *(uint4*)(hi + (size_t)(n0 + r) * K + k0 + c) = *(const uint4*)&ht[r][c];
    *(uint4*)(lo + (size_t)(n0 + r) * K + k0 + c) = *(const uint4*)&lt[r][c];
  }
}

// ---------------------------------------------------------------------------
// MFMA split-fp16 GEMM — round-7/11 triple-buffer body (measured plateau:
// G1 = 299.5-307 us, MfmaUtil 48, 0 conflicts). Fused max|C| epilogue.
// ---------------------------------------------------------------------------
#define STAGE_A(tt, dst) do {                                                  \
    const _Float16* As_ = ((tt) < 64) ? Ahi : Alo;                             \
    const size_t so_ = (size_t)(row0 + wave * 8 + srow) * KS +                 \
                       (((tt) & 31) << 6) + schunk;                            \
    _Float16* db_ = (dst) + wave * 512;                                        \
    gl_lds16(As_ + so_,                    db_);                               \
    gl_lds16(As_ + so_ + (size_t)64 * KS,  db_ + 4096);                        \
    gl_lds16(As_ + so_ + (size_t)128 * KS, db_ + 8192);                       \
    gl_lds16(As_ + so_ + (size_t)192 * KS, db_ + 12288);                       \
  } while (0)

#define STAGE_B(tt, dst) do {                                                  \
    const _Float16* Bs_ = ((((tt) >> 5)) == 1) ? Btlo : Bthi;                  \
    const size_t so_ = (size_t)(col0 + wave * 8 + srow) * KS +                 \
                       (((tt) & 31) << 6) + schunk;                            \
    _Float16* db_ = (dst) + 16384 + wave * 512;                                \
    gl_lds16(Bs_ + so_,                    db_);                               \
    gl_lds16(Bs_ + so_ + (size_t)64 * KS,  db_ + 4096);                        \
  } while (0)

__global__ __launch_bounds__(512, 2) void gemm_split256(
    const _Float16* __restrict__ Ahi, const _Float16* __restrict__ Alo,
    const _Float16* __restrict__ Bthi, const _Float16* __restrict__ Btlo,
    float* __restrict__ C, const float* __restrict__ bias,
    unsigned* mx, int N, int has_bias) {
  __shared__ __align__(16) _Float16 lds[73728];   // 3 x 48 KiB = 144 KiB
  const int t = threadIdx.x;
  const int wave = t >> 6, lane = t & 63;
  const int l15 = lane & 15, g = lane >> 4;
  const int wm = wave >> 1, wn = wave & 1;    // 4M x 2N wave grid

  // XCD-aware bijective tile swizzle (both grids are multiples of 8)
  const int gx = gridDim.x;
  const int nwg = gx * gridDim.y;
  const int bid = blockIdx.y * gx + blockIdx.x;
  const int tile = (bid & 7) * (nwg >> 3) + (bid >> 3);
  const int row0 = (tile / gx) * 256, col0 = (tile % gx) * 128;

  // staging coords: 8 rows x 128B per wave per load; source chunk XOR-swizzled
  const int srow = lane >> 3;                    // row&7 of staged row
  const int schunk = ((lane & 7) ^ srow) << 3;   // halves

  f32x4 acc[4][4] = {};

  _Float16* bufA = lds;                 // tile kc   (compute)
  _Float16* bufB = lds + 24576;         // tile kc+1 (in flight / landed)
  _Float16* bufC = lds + 49152;         // tile kc+2 (stage target)

  // prologue: tile0 -> bufA, tile1 -> bufB; retire tile0 (6), keep tile1 flying
  STAGE_A(0, bufA);
  STAGE_B(0, bufA);
  STAGE_A(1, bufB);
  STAGE_B(1, bufB);
  asm volatile("s_waitcnt vmcnt(6)" ::: "memory");
  __builtin_amdgcn_s_barrier();

  for (int kc = 0; kc < 96; kc++) {
    const _Float16* Ab = bufA;
    const _Float16* Bb = bufA + 16384;
    f16x8 af0[4], bf0[4], af1[4], bf1[4];
#pragma unroll
    for (int i = 0; i < 4; i++) {
      const int r_ = wm * 64 + i * 16 + l15;
      af0[i] = *(const f16x8*)(Ab + r_ * 64 + ((g ^ (r_ & 7)) << 3));
      af1[i] = *(const f16x8*)(Ab + r_ * 64 + (((4 ^ g) ^ (r_ & 7)) << 3));
    }
#pragma unroll
    for (int j = 0; j < 4; j++) {
      const int r_ = wn * 64 + j * 16 + l15;
      bf0[j] = *(const f16x8*)(Bb + r_ * 64 + ((g ^ (r_ & 7)) << 3));
      bf1[j] = *(const f16x8*)(Bb + r_ * 64 + (((4 ^ g) ^ (r_ & 7)) << 3));
    }
    // stage tile kc+2 into the buffer freed at the end of kc-1
    if (kc + 2 < 96) {
      STAGE_A(kc + 2, bufC);
      STAGE_B(kc + 2, bufC);
    }
    // k-half 0 then k-half 1 (accumulation order identical to prior rounds)
#pragma unroll
    for (int i = 0; i < 4; i++)
#pragma unroll
      for (int j = 0; j < 4; j++)
        acc[i][j] = __builtin_amdgcn_mfma_f32_16x16x32_f16(af0[i], bf0[j], acc[i][j], 0, 0, 0);
#pragma unroll
    for (int i = 0; i < 4; i++)
#pragma unroll
      for (int j = 0; j < 4; j++)
        acc[i][j] = __builtin_amdgcn_mfma_f32_16x16x32_f16(af1[i], bf1[j], acc[i][j], 0, 0, 0);
    // retire tile kc+1's 6 loads; keep tile kc+2's 6 in flight
    if (kc < 94) { asm volatile("s_waitcnt vmcnt(6)" ::: "memory"); }
    else         { asm volatile("s_waitcnt vmcnt(0)" ::: "memory"); }
    __builtin_amdgcn_s_barrier();
    _Float16* tmp = bufA; bufA = bufB; bufB = bufC; bufC = tmp;
  }

  float bmax = 0.0f;
#pragma unroll
  for (int j = 0; j < 4; j++) {
    const int col = col0 + wn * 64 + j * 16 + l15;
    const float bv = has_bias ? bias[col] : 0.0f;
#pragma unroll
    for (int i = 0; i < 4; i++) {
      const int rbase = row0 + wm * 64 + i * 16 + g * 4;
#pragma unroll
      for (int r = 0; r < 4; r++) {
        const float v = acc[i][j][r] + bv;
        C[(size_t)(rbase + r) * N + col] = v;
        bmax = fmaxf(bmax, fabsf(v));
      }
    }
  }

  // fused per-segment max|.| (gemm1 only): block lies wholly in segment col0>>11
  if (mx) {
    __syncthreads();                 // K-loop done; LDS free for reduction
    float* red = (float*)lds;
    red[t] = bmax;
    __syncthreads();
    for (int s2 = 256; s2 > 0; s2 >>= 1) {
      if (t < s2) red[t] = fmaxf(red[t], red[t + s2]);
      __syncthreads();
    }
    if (t == 0) atomicMax(mx + (col0 >> 11), __float_as_uint(red[0]));
  }
}

// ---------------------------------------------------------------------------
// Fused quantization: Q,K segments -> q8/k8 [bh][s][d]; V -> v8t[bh][d][s]
// ---------------------------------------------------------------------------
__global__ __launch_bounds__(256) void quant_qkv(
    const float* __restrict__ qkv, const unsigned* __restrict__ mx,
    _Float16* __restrict__ q8, _Float16* __restrict__ k8,
    _Float16* __restrict__ v8t) {
  __shared__ _Float16 tile[64 * 72];
  const int t = threadIdx.x;
  const int bid = blockIdx.x;

  if (bid < 16384) {
    // ---- Q/K path ----
    const size_t base = ((size_t)bid * 256 + t) * 4;
    const int row = (int)(base >> 12);
    const int col = (int)(base & 4095);
    const int seg = col >> 11;
    const int c2 = col & 2047;
    const int h = c2 >> 7, d = c2 & 127;
    const int b = row >> 11, s = row & 2047;
    const float scale = __uint_as_float(mx[seg]) / 448.0f;
    float4 v = *(const float4*)(qkv + (size_t)row * F3 + col);
    H4 r;
    r.h[0] = (_Float16)quant_e4m3(v.x / scale);
    r.h[1] = (_Float16)quant_e4m3(v.y / scale);
    r.h[2] = (_Float16)quant_e4m3(v.z / scale);
    r.h[3] = (_Float16)quant_e4m3(v.w / scale);
    _Float16* dst = seg ? k8 : q8;
    const size_t di = ((size_t)((b * NH + h) * S_) + s) * HD + d;
    *(ushort4*)(dst + di) = r.s4;
  } else {
    // ---- V path (transposed store) ----
    const int bt = bid - 16384;
    const int dtile = bt & 1;
    const int stile = (bt >> 1) & 31;
    const int bh = bt >> 6;
    const int b = bh >> 4, h = bh & 15;
    const int s0 = stile * 64, d0 = dtile * 64;
    const float scale = __uint_as_float(mx[2]) / 448.0f;

#pragma unroll
    for (int r = 0; r < 4; r++) {
      const int s = s0 + r * 16 + (t >> 4);
      const int dl = (t & 15) * 4;
      float4 v = *(const float4*)(qkv + (size_t)(b * S_ + s) * F3 + 4096 + h * HD + d0 + dl);
      tile[(dl + 0) * 72 + r * 16 + (t >> 4)] = (_Float16)quant_e4m3(v.x / scale);
      tile[(dl + 1) * 72 + r * 16 + (t >> 4)] = (_Float16)quant_e4m3(v.y / scale);
      tile[(dl + 2) * 72 + r * 16 + (t >> 4)] = (_Float16)quant_e4m3(v.z / scale);
      tile[(dl + 3) * 72 + r * 16 + (t >> 4)] = (_Float16)quant_e4m3(v.w / scale);
    }
    __syncthreads();
#pragma unroll
    for (int j = 0; j < 2; j++) {
      const int wi = j * 256 + t;
      const int dl = wi >> 3;
      const int sch = (wi & 7) * 8;
      uint4 val = *(const uint4*)(tile + dl * 72 + sch);
      *(uint4*)(v8t + (size_t)bh * (HD * S_) + (size_t)(d0 + dl) * S_ + s0 + sch) = val;
    }
  }
}

// ---------------------------------------------------------------------------
// MFMA flash attention, round-18: QK^T software-pipelined ONE TILE AHEAD.
// Per kt: {write K/V(kt+1); issue loads kt+2; MID barrier; QK(kt+1) MFMAs
// (independent) OVERLAP softmax+pack(kt) VALU; PV(kt); END barrier}.
// MFMA pipe covers the serial softmax chain (separate pipes, m114).
// Buffer lifetimes: Kbuf[j&1] last read by QK(j) in iter j-1, overwritten
// top of j+1 (2 barriers apart); Vbuf[j&1] read by PV(j) before end-bar(j),
// overwritten top of j+1. All MFMA/add orders unchanged -> bit-identical.
// ---------------------------------------------------------------------------
__global__ __launch_bounds__(256, 2) void attn_kernel(
    const _Float16* __restrict__ q8, const _Float16* __restrict__ k8,
    const _Float16* __restrict__ v8t, const unsigned* __restrict__ mx,
    _Float16* __restrict__ oHi, _Float16* __restrict__ oLo) {
  __shared__ __align__(16) char ldsb[65536];
  // K buffers: ldsb + {0, 16384}   : [64 keys][128 halves], chunk^=(row&7)
  // V buffers: ldsb + {32768, 49152}: [128 d][64 halves],   chunk^=(row&7)

  const int t = threadIdx.x;        // 0..255
  const int wave = t >> 6;          // 0..3
  const int lane = t & 63;
  const int l31 = lane & 31;
  const int hf = lane >> 5;

  const int qt = blockIdx.x & 15;
  const int bh = blockIdx.x >> 4;
  const int b = bh >> 4, h = bh & 15;
  const int q0 = qt * 128 + wave * 32;   // this wave's 32 queries

  const float qs = __uint_as_float(mx[0]) * (1.0f / 448.0f);
  const float ks = __uint_as_float(mx[1]) * (1.0f / 448.0f);
  const float vs = __uint_as_float(mx[2]) * (1.0f / 448.0f);
  const float sfac = qs * ks * 0.08838834764831843f;   // 1/sqrt(128)

  // Q fragments (B-layout): Q[q=l31][d = st*16 + hf*8 + j]
  f16x8 qf[8];
  {
    const _Float16* qp = q8 + ((size_t)(bh * S_) + q0 + l31) * HD + hf * 8;
#pragma unroll
    for (int st = 0; st < 8; st++)
      qf[st] = *(const f16x8*)(qp + st * 16);
  }

  f32x16 acc[4] = {};
  float m_base = 0.0f;
  float l_run = 0.0f;

  const size_t kB_ = (size_t)(bh * S_) * HD;
  const size_t vB_ = (size_t)bh * (HD * S_);
  // per-thread staging coordinates
  const int k_key = t >> 4;            // + r*16 ; row&7 = k_key&7
  const int k_dch = (t & 15) * 8;      // global chunk offset (halves)
  const int k_wch = (((t & 15) ^ (k_key & 7)) << 3);   // swizzled LDS chunk
  const int v_d   = t >> 3;            // + r*32 ; row&7 = v_d&7
  const int v_sch = (t & 7) * 8;       // global chunk offset (halves)
  const int v_wch = (((t & 7) ^ (v_d & 7)) << 3);      // swizzled LDS chunk

  const int NT = S_ / 64;              // 32
  uint4 kp[4], vp[4];

  // prologue: tile0 -> buffers[0]; issue tile1 loads; barrier; QK(0)
#pragma unroll
  for (int r = 0; r < 4; r++)
    kp[r] = *(const uint4*)(k8 + kB_ + (size_t)(r * 16 + k_key) * HD + k_dch);
#pragma unroll
  for (int r = 0; r < 4; r++)
    vp[r] = *(const uint4*)(v8t + vB_ + (size_t)(r * 32 + v_d) * S_ + v_sch);
  {
    _Float16* K0 = (_Float16*)ldsb;
    _Float16* V0 = (_Float16*)(ldsb + 32768);
#pragma unroll
    for (int r = 0; r < 4; r++)
      *(uint4*)(K0 + (r * 16 + k_key) * 128 + k_wch) = kp[r];
#pragma unroll
    for (int r = 0; r < 4; r++)
      *(uint4*)(V0 + (r * 32 + v_d) * 64 + v_wch) = vp[r];
  }
#pragma unroll
  for (int r = 0; r < 4; r++)
    kp[r] = *(const uint4*)(k8 + kB_ + (size_t)(64 + r * 16 + k_key) * HD + k_dch);
#pragma unroll
  for (int r = 0; r < 4; r++)
    vp[r] = *(const uint4*)(v8t + vB_ + (size_t)(r * 32 + v_d) * S_ + 64 + v_sch);
  __syncthreads();

  // s_cur = QK(0): two interleaved independent chains (2-way ILP)
  f32x16 sc0 = {}, sc1 = {};
  {
    const _Float16* K0 = (const _Float16*)ldsb;
    __builtin_amdgcn_s_setprio(1);
#pragma unroll
    for (int st = 0; st < 8; st++) {
      const int kr0 = l31, kr1 = 32 + l31;
      f16x8 a0 = *(const f16x8*)(K0 + kr0 * 128 + (((st * 2 + hf) ^ (kr0 & 7)) << 3));
      f16x8 a1 = *(const f16x8*)(K0 + kr1 * 128 + (((st * 2 + hf) ^ (kr1 & 7)) << 3));
      sc0 = __builtin_amdgcn_mfma_f32_32x32x16_f16(a0, qf[st], sc0, 0, 0, 0);
      sc1 = __builtin_amdgcn_mfma_f32_32x32x16_f16(a1, qf[st], sc1, 0, 0, 0);
    }
    __builtin_amdgcn_s_setprio(0);
  }

  for (int kt = 0; kt < NT; kt++) {
    // ---- top: write tile kt+1 into the other buffers; issue loads kt+2 ----
    if (kt + 1 < NT) {
      _Float16* Kn = (_Float16*)(ldsb + ((kt + 1) & 1) * 16384);
      _Float16* Vn = (_Float16*)(ldsb + 32768 + ((kt + 1) & 1) * 16384);
#pragma unroll
      for (int r = 0; r < 4; r++)
        *(uint4*)(Kn + (r * 16 + k_key) * 128 + k_wch) = kp[r];
#pragma unroll
      for (int r = 0; r < 4; r++)
        *(uint4*)(Vn + (r * 32 + v_d) * 64 + v_wch) = vp[r];
    }
    if (kt + 2 < NT) {
      const int nk = (kt + 2) * 64;
#pragma unroll
      for (int r = 0; r < 4; r++)
        kp[r] = *(const uint4*)(k8 + kB_ + (size_t)(nk + r * 16 + k_key) * HD + k_dch);
#pragma unroll
      for (int r = 0; r < 4; r++)
        vp[r] = *(const uint4*)(v8t + vB_ + (size_t)(r * 32 + v_d) * S_ + nk + v_sch);
    }
    __syncthreads();   // MID: K/V(kt+1) visible to all waves

    // ---- QK(kt+1) MFMAs — overlap the softmax/pack VALU below ----
    f32x16 sn0 = {}, sn1 = {};
    if (kt + 1 < NT) {
      const _Float16* Kn = (const _Float16*)(ldsb + ((kt + 1) & 1) * 16384);
      __builtin_amdgcn_s_setprio(1);
#pragma unroll
      for (int st = 0; st < 8; st++) {
        const int kr0 = l31, kr1 = 32 + l31;
        f16x8 a0 = *(const f16x8*)(Kn + kr0 * 128 + (((st * 2 + hf) ^ (kr0 & 7)) << 3));
        f16x8 a1 = *(const f16x8*)(Kn + kr1 * 128 + (((st * 2 + hf) ^ (kr1 & 7)) << 3));
        sn0 = __builtin_amdgcn_mfma_f32_32x32x16_f16(a0, qf[st], sn0, 0, 0, 0);
        sn1 = __builtin_amdgcn_mfma_f32_32x32x16_f16(a1, qf[st], sn1, 0, 0, 0);
      }
      __builtin_amdgcn_s_setprio(0);
    }

    const _Float16* VTlds = (const _Float16*)(ldsb + 32768 + (kt & 1) * 16384);
    // prefetch dt=0 V fragments for both subs
    f16x8 vf00 = *(const f16x8*)(VTlds + l31 * 64 + (((0 + hf) ^ (l31 & 7)) << 3));
    f16x8 vf01 = *(const f16x8*)(VTlds + l31 * 64 + (((2 + hf) ^ (l31 & 7)) << 3));
    f16x8 vf10 = *(const f16x8*)(VTlds + l31 * 64 + (((4 + hf) ^ (l31 & 7)) << 3));
    f16x8 vf11 = *(const f16x8*)(VTlds + l31 * 64 + (((6 + hf) ^ (l31 & 7)) << 3));

    // ---- fixed-base softmax weights on s_cur (sub0 then sub1) ----
    float p0[16], p1[16];
    if (kt == 0) {
      float tmax = -3.0e38f;
#pragma unroll
      for (int i = 0; i < 16; i++) {
        p0[i] = sc0[i] * sfac;
        tmax = fmaxf(tmax, p0[i]);
      }
      tmax = fmaxf(tmax, __shfl_xor(tmax, 32));
      m_base = tmax;
      float rs = 0.0f;
#pragma unroll
      for (int i = 0; i < 16; i++) {
        p0[i] = __expf(p0[i] - tmax);
        rs += p0[i];
      }
      l_run += rs;
    } else {
      const float mb = m_base;
      float rs = 0.0f;
#pragma unroll
      for (int i = 0; i < 16; i++) {
        p0[i] = fminf(__expf(fmaf(sc0[i], sfac, -mb)), 60000.0f);
        rs += p0[i];
      }
      l_run += rs;
    }
    {
      const float mb = m_base;
      float rs = 0.0f;
#pragma unroll
      for (int i = 0; i < 16; i++) {
        p1[i] = fminf(__expf(fmaf(sc1[i], sfac, -mb)), 60000.0f);
        rs += p1[i];
      }
      l_run += rs;
    }

    // ---- pack + cross-half exchange -> P^T B-frags (both subs) ----
    f16x8 pf0[2], pf1[2];
#pragma unroll
    for (int sb = 0; sb < 2; sb++) {
      const float* pp = sb ? p1 : p0;
      f16x8* pf = sb ? pf1 : pf0;
#pragma unroll
      for (int c = 0; c < 2; c++) {
        const int c8 = c * 8;
        const int sidx = hf ? 0 : 4;
        const int oidx = hf ? 4 : 0;
        H2 s0h, s1h, o0h, o1h;
        s0h.h[0] = (_Float16)pp[c8 + sidx];     s0h.h[1] = (_Float16)pp[c8 + sidx + 1];
        s1h.h[0] = (_Float16)pp[c8 + sidx + 2]; s1h.h[1] = (_Float16)pp[c8 + sidx + 3];
        o0h.h[0] = (_Float16)pp[c8 + oidx];     o0h.h[1] = (_Float16)pp[c8 + oidx + 1];
        o1h.h[0] = (_Float16)pp[c8 + oidx + 2]; o1h.h[1] = (_Float16)pp[c8 + oidx + 3];
        unsigned r0 = (unsigned)__shfl_xor((int)s0h.u, 32);
        unsigned r1 = (unsigned)__shfl_xor((int)s1h.u, 32);
        PU pu;
        if (hf == 0) { pu.u[0] = o0h.u; pu.u[1] = o1h.u; pu.u[2] = r0; pu.u[3] = r1; }
        else         { pu.u[0] = r0;    pu.u[1] = r1;    pu.u[2] = o0h.u; pu.u[3] = o1h.u; }
        pf[c] = pu.v8;
      }
    }

    // ---- O^T += V^T . P^T  (per-acc order: sub0 c0,c1 then sub1 c0,c1) ----
#pragma unroll
    for (int dt = 0; dt < 4; dt++) {
      f16x8 n00, n01, n10, n11;
      if (dt < 3) {
        const int vrow = (dt + 1) * 32 + l31;
        n00 = *(const f16x8*)(VTlds + vrow * 64 + (((0 + hf) ^ (vrow & 7)) << 3));
        n01 = *(const f16x8*)(VTlds + vrow * 64 + (((2 + hf) ^ (vrow & 7)) << 3));
        n10 = *(const f16x8*)(VTlds + vrow * 64 + (((4 + hf) ^ (vrow & 7)) << 3));
        n11 = *(const f16x8*)(VTlds + vrow * 64 + (((6 + hf) ^ (vrow & 7)) << 3));
      }
      __builtin_amdgcn_s_setprio(1);
      acc[dt] = __builtin_amdgcn_mfma_f32_32x32x16_f16(vf00, pf0[0], acc[dt], 0, 0, 0);
      acc[dt] = __builtin_amdgcn_mfma_f32_32x32x16_f16(vf01, pf0[1], acc[dt], 0, 0, 0);
      acc[dt] = __builtin_amdgcn_mfma_f32_32x32x16_f16(vf10, pf1[0], acc[dt], 0, 0, 0);
      acc[dt] = __builtin_amdgcn_mfma_f32_32x32x16_f16(vf11, pf1[1], acc[dt], 0, 0, 0);
      __builtin_amdgcn_s_setprio(0);
      vf00 = n00; vf01 = n01; vf10 = n10; vf11 = n11;
    }
    __syncthreads();   // END: PV(kt) reads done before V(kt+2) writes
    sc0 = sn0; sc1 = sn1;
  }

  // combine the two half-lane partial sums of l
  l_run += __shfl_xor(l_run, 32);
  const float f = vs / l_run;

  // ---- epilogue: stage fp16 in LDS, store FULL 256B lines (2 passes) ----
  // obuf: [4 waves][32 q][136 halves]; value at [q][dt*32+dl]
  _Float16* obuf = (_Float16*)ldsb;
  const int obase = wave * 4352;       // 32*136 halves
#pragma unroll
  for (int pass = 0; pass < 2; pass++) {
    __syncthreads();                   // K/V loop done / previous pass stored
#pragma unroll
    for (int dt = 0; dt < 4; dt++) {
#pragma unroll
      for (int iq = 0; iq < 4; iq++) { // i = iq*4 .. iq*4+3 -> dl0..dl0+3
        const int dl0 = 8 * iq + 4 * hf;
        H4b w;
#pragma unroll
        for (int e = 0; e < 4; e++) {
          const float o = acc[dt][iq * 4 + e] * f;
          const _Float16 hh = (_Float16)o;
          w.h[e] = pass ? (_Float16)(o - (float)hh) : hh;
        }
        *(uint2*)&obuf[obase + l31 * 136 + dt * 32 + dl0] = w.u2;
      }
    }
    __syncthreads();
    _Float16* dst = pass ? oLo : oHi;
#pragma unroll
    for (int ii = 0; ii < 8; ii++) {
      const int qrow = ii * 4 + (lane >> 4);
      const int ch = (lane & 15) * 8;  // halves within the 128-wide row
      uint4 val = *(const uint4*)&obuf[obase + qrow * 136 + ch];
      const size_t ofs = (size_t)(b * S_ + q0 + qrow) * H_ + h * HD + ch;
      *(uint4*)(dst + ofs) = val;
    }
  }
}

// ---------------------------------------------------------------------------
extern "C" void kernel_launch(void* const* d_in, const int* in_sizes, int n_in,
                              void* d_out, int out_size, void* d_ws, size_t ws_size,
                              hipStream_t stream) {
  const float* x     = (const float*)d_in[0];
  const float* W_qkv = (const float*)d_in[1];
  const float* W_out = (const float*)d_in[2];
  const float* b_out = (const float*)d_in[3];
  float* out = (float*)d_out;

  char* ws = (char*)d_ws;
  // Region 0 [0, 100.66 MB): qkv fp32; later A2 splits (attn output) + B2t
  float*    qkv    = (float*)ws;
  _Float16* A2hi   = (_Float16*)(ws + 33554432);               // 16,777,216 B
  _Float16* A2lo   = (_Float16*)(ws + 50331648);
  _Float16* B2thi  = (_Float16*)(ws + 67108864);               //  8,388,608 B
  _Float16* B2tlo  = (_Float16*)(ws + 75497472);
  // Region 1 [100.66, 151.0 MB): B1t splits, then reused for q8/k8/v8t
  _Float16* B1thi  = (_Float16*)(ws + 100663296);              // 25,165,824 B
  _Float16* B1tlo  = (_Float16*)(ws + 125829120);
  _Float16* q8     = (_Float16*)(ws + 100663296);              // 16,777,216 B
  _Float16* k8     = (_Float16*)(ws + 117440512);
  _Float16* v8t    = (_Float16*)(ws + 134217728);
  // Region 2 [151.0, 184.6 MB): A1 splits
  _Float16* A1hi   = (_Float16*)(ws + 150994944);
  _Float16* A1lo   = (_Float16*)(ws + 167772160);
  unsigned* mx     = (unsigned*)(ws + 184549376);

  hipMemsetAsync(mx, 0, 3 * sizeof(unsigned), stream);

  // fused prep: x -> A1 splits (8192 blocks) + W_qkv^T -> B1t (3072 blocks)
  prep_split<<<11264, 256, 0, stream>>>(x, W_qkv, A1hi, A1lo, B1thi, B1tlo);

  // qkv = x @ W_qkv  (split-fp16 MFMA, K' = 6144); 48x16 = 768 blocks
  // + fused per-segment max|qkv| -> mx
  gemm_split256<<<dim3(F3 / 128, ROWS / 256), 512, 0, stream>>>(
      A1hi, A1lo, B1thi, B1tlo, qkv, nullptr, mx, F3, 0);

  // fused quantization of Q,K (16384 blocks) and V-transposed (2048 blocks)
  quant_qkv<<<16384 + B_ * NH * 32 * 2, 256, 0, stream>>>(qkv, mx, q8, k8, v8t);

  // attention -> writes out-proj A-operand hi/lo directly
  attn_kernel<<<B_ * NH * 16, 256, 0, stream>>>(q8, k8, v8t, mx, A2hi, A2lo);

  // split W_out^T (B2t) — must follow quant_qkv (B2t aliases qkv region)
  split_tr<<<dim3(H_ / 64, H_ / 64), 256, 0, stream>>>(W_out, B2thi, B2tlo, H_, H_);

  // out = attn_out @ W_out + b_out; 16x16 = 256 blocks
  gemm_split256<<<dim3(H_ / 128, ROWS / 256), 512, 0, stream>>>(
      A2hi, A2lo, B2thi, B2tlo, out, b_out, nullptr, H_, 1);
}